// Round 1
// baseline (326.482 us; speedup 1.0000x reference)
//
#include <hip/hip_runtime.h>
#include <hip/hip_bf16.h>
#include <math.h>

// Problem constants (B=4, T=1024, C=768, E=8, K=2)
#define N_TOK 4096
#define CDIM  768
#define E_EXP 8
#define CAPC  2048
#define HDIM  3072   // 4*C

typedef __attribute__((ext_vector_type(8))) short short8;
typedef __attribute__((ext_vector_type(4))) float floatx4;

static __device__ __forceinline__ unsigned short f2bf(float f) {
  __hip_bfloat16 h = __float2bfloat16(f);
  return __builtin_bit_cast(unsigned short, h);
}

// ---------------------------------------------------------------------------
// K1: transpose + f32->bf16 convert.  in: [E][R][Cc] f32 row-major
//                                     out: [E][Cc][R] bf16 row-major
// ---------------------------------------------------------------------------
__global__ __launch_bounds__(256)
void transpose_convert(const float* __restrict__ in, __hip_bfloat16* __restrict__ out,
                       int R, int Cc)
{
  __shared__ float tile[32][33];
  const int e  = blockIdx.z;
  const int c0 = blockIdx.x * 32;   // along Cc
  const int r0 = blockIdx.y * 32;   // along R
  const float* ie = in + (size_t)e * R * Cc;
  __hip_bfloat16* oe = out + (size_t)e * Cc * R;
  const int t = threadIdx.x;
  {
    const int r = t >> 3, c = (t & 7) * 4;
    const float4 v = *(const float4*)(ie + (size_t)(r0 + r) * Cc + c0 + c);
    tile[r][c + 0] = v.x; tile[r][c + 1] = v.y; tile[r][c + 2] = v.z; tile[r][c + 3] = v.w;
  }
  __syncthreads();
  {
    const int cc = t >> 3, rr = (t & 7) * 4;
    ushort4 o;
    o.x = f2bf(tile[rr + 0][cc]);
    o.y = f2bf(tile[rr + 1][cc]);
    o.z = f2bf(tile[rr + 2][cc]);
    o.w = f2bf(tile[rr + 3][cc]);
    *(ushort4*)((unsigned short*)oe + (size_t)(c0 + cc) * R + r0 + rr) = o;
  }
}

// ---------------------------------------------------------------------------
// K2: router — logits = x @ w_g^T, top-2 + softmax over the two kept logits.
// One wave per token.  eidx/pval layout: [2][N] (k-major, matching reference).
// ---------------------------------------------------------------------------
__global__ __launch_bounds__(256)
void router_kernel(const float* __restrict__ x, const float* __restrict__ wg,
                   int* __restrict__ eidx, float* __restrict__ pval)
{
  const int wv = threadIdx.x >> 6, lane = threadIdx.x & 63;
  const int n = blockIdx.x * 4 + wv;
  const float* xr = x + (size_t)n * CDIM;
  float acc[E_EXP] = {0.f, 0.f, 0.f, 0.f, 0.f, 0.f, 0.f, 0.f};
#pragma unroll
  for (int i = 0; i < CDIM / 64; ++i) {
    const float xv = xr[i * 64 + lane];
#pragma unroll
    for (int e = 0; e < E_EXP; ++e)
      acc[e] = fmaf(xv, wg[e * CDIM + i * 64 + lane], acc[e]);
  }
#pragma unroll
  for (int e = 0; e < E_EXP; ++e) {
#pragma unroll
    for (int off = 32; off > 0; off >>= 1)
      acc[e] += __shfl_xor(acc[e], off);
  }
  if (lane == 0) {
    int e0 = 0; float v0 = acc[0];
#pragma unroll
    for (int e = 1; e < E_EXP; ++e) if (acc[e] > v0) { v0 = acc[e]; e0 = e; }
    int e1 = -1; float v1 = -3.4e38f;
#pragma unroll
    for (int e = 0; e < E_EXP; ++e) if (e != e0 && acc[e] > v1) { v1 = acc[e]; e1 = e; }
    const float ex = __expf(v1 - v0) ;
    const float inv = 1.f / (1.f + ex);
    eidx[n] = e0; eidx[N_TOK + n] = e1;
    pval[n] = inv; pval[N_TOK + n] = ex * inv;
  }
}

// ---------------------------------------------------------------------------
// K3: init slot_token to -1
// ---------------------------------------------------------------------------
__global__ void init_slots(int* __restrict__ p)
{
  p[blockIdx.x * 256 + threadIdx.x] = -1;
}

// ---------------------------------------------------------------------------
// K4: capacity scan.  Assignment a = k*N + n (k-major reference order).
// rank(a) = #{a' < a : expert(a') == expert(a)}; keep if rank < CAP.
// Single block, 256 threads x 32 assignments, Hillis-Steele per-expert scan.
// ---------------------------------------------------------------------------
__global__ __launch_bounds__(256)
void scan_kernel(const int* __restrict__ eidx, int* __restrict__ slot,
                 int* __restrict__ slot_token)
{
  const int t = threadIdx.x;
  const int base = t * 32;
  int e_local[32];
  int cnt[E_EXP] = {0, 0, 0, 0, 0, 0, 0, 0};
#pragma unroll
  for (int i = 0; i < 32; ++i) {
    const int e = eidx[base + i];
    e_local[i] = e;
    cnt[e]++;
  }
  __shared__ int hist[256][E_EXP];
#pragma unroll
  for (int e = 0; e < E_EXP; ++e) hist[t][e] = cnt[e];
  __syncthreads();
  for (int off = 1; off < 256; off <<= 1) {
    int v[E_EXP] = {0, 0, 0, 0, 0, 0, 0, 0};
    if (t >= off) {
#pragma unroll
      for (int e = 0; e < E_EXP; ++e) v[e] = hist[t - off][e];
    }
    __syncthreads();
    if (t >= off) {
#pragma unroll
      for (int e = 0; e < E_EXP; ++e) hist[t][e] += v[e];
    }
    __syncthreads();
  }
  int run[E_EXP];
#pragma unroll
  for (int e = 0; e < E_EXP; ++e) run[e] = hist[t][e] - cnt[e];  // exclusive prefix
#pragma unroll
  for (int i = 0; i < 32; ++i) {
    const int a = base + i;
    const int e = e_local[i];
    const int r = run[e]++;
    const int s = (r < CAPC) ? r : -1;
    slot[a] = s;
    if (s >= 0) slot_token[e * CAPC + s] = (a < N_TOK) ? a : (a - N_TOK);
  }
}

// ---------------------------------------------------------------------------
// K5: dispatch — exp_in[e][c][:] = bf16(x[token]) or zeros.  One wave/slot.
// ---------------------------------------------------------------------------
__global__ __launch_bounds__(256)
void dispatch_kernel(const float* __restrict__ x, const int* __restrict__ slot_token,
                     __hip_bfloat16* __restrict__ xin)
{
  const int wv = threadIdx.x >> 6, lane = threadIdx.x & 63;
  const int s = blockIdx.x * 4 + wv;
  const int n = slot_token[s];
  unsigned short* orow = (unsigned short*)xin + (size_t)s * CDIM;
  if (n >= 0) {
    const float4* xr = (const float4*)(x + (size_t)n * CDIM);
#pragma unroll
    for (int i = 0; i < 3; ++i) {
      const float4 v = xr[i * 64 + lane];
      ushort4 o;
      o.x = f2bf(v.x); o.y = f2bf(v.y); o.z = f2bf(v.z); o.w = f2bf(v.w);
      *(ushort4*)(orow + (size_t)(i * 64 + lane) * 4) = o;
    }
  } else {
    const ushort4 z = {0, 0, 0, 0};
#pragma unroll
    for (int i = 0; i < 3; ++i)
      *(ushort4*)(orow + (size_t)(i * 64 + lane) * 4) = z;
  }
}

// ---------------------------------------------------------------------------
// K6: batched GEMM  C[e] = A[e](MxK) @ Bt[e](NxK)^T + bias[e]
// m97-style: 128x128 tile, BK=64, 4 waves (2x2 of 64x64), 16x16x32 bf16 MFMA,
// global_load_lds(16B) staging with both-sides XOR swizzle (kb ^= (row&7)<<4).
// GELU_OUT=1: bf16 out with exact GELU;  GELU_OUT=0: f32 out plain.
// ---------------------------------------------------------------------------
template<int GELU_OUT>
__global__ __launch_bounds__(256)
void gemm_kernel(const __hip_bfloat16* __restrict__ A,
                 const __hip_bfloat16* __restrict__ Bt,
                 const float* __restrict__ bias,
                 void* __restrict__ Cout,
                 int M, int Nn, int K)
{
  __shared__ __hip_bfloat16 As[128 * 64];
  __shared__ __hip_bfloat16 Bs[128 * 64];
  const int e  = blockIdx.z;
  const int n0 = blockIdx.x * 128;
  const int m0 = blockIdx.y * 128;
  const int t = threadIdx.x;
  const int wv = t >> 6, lane = t & 63;

  const __hip_bfloat16* Ae = A  + (size_t)e * M  * K + (size_t)m0 * K;
  const __hip_bfloat16* Be = Bt + (size_t)e * Nn * K + (size_t)n0 * K;

  // staging geometry: per issue i, this wave fills LDS bytes
  // [i*4096 + wv*1024, +1024); lane covers base + lane*16 (HW scatter).
  const int srow = wv * 8 + (lane >> 3);    // row within the 32-row issue chunk
  const int skb  = (lane & 7) * 16;         // linear k-byte within the 128B row

  const int wr = wv >> 1, wc = wv & 1;      // 2x2 wave grid
  const int fr = lane & 15, fk = lane >> 4; // fragment row/col, k-subgroup

  floatx4 acc[4][4] = {};

  for (int k0 = 0; k0 < K; k0 += 64) {
    __syncthreads();
#pragma unroll
    for (int i = 0; i < 4; ++i) {
      const int row = i * 32 + srow;
      const int kb  = skb ^ ((row & 7) << 4);   // pre-swizzled global source
      const char* gA = (const char*)(Ae + (size_t)row * K + k0) + kb;
      const char* gB = (const char*)(Be + (size_t)row * K + k0) + kb;
      char* lA = (char*)As + i * 4096 + wv * 1024;
      char* lB = (char*)Bs + i * 4096 + wv * 1024;
      __builtin_amdgcn_global_load_lds((const __attribute__((address_space(1))) unsigned int*)gA,
                                       (__attribute__((address_space(3))) unsigned int*)lA, 16, 0, 0);
      __builtin_amdgcn_global_load_lds((const __attribute__((address_space(1))) unsigned int*)gB,
                                       (__attribute__((address_space(3))) unsigned int*)lB, 16, 0, 0);
    }
    __syncthreads();
#pragma unroll
    for (int kk = 0; kk < 2; ++kk) {
      short8 afr[4], bfr[4];
#pragma unroll
      for (int mi = 0; mi < 4; ++mi) {
        const int row = wr * 64 + mi * 16 + fr;
        const int kb  = (kk * 64 + fk * 16) ^ ((row & 7) << 4);
        afr[mi] = *(const short8*)((const char*)As + row * 128 + kb);
      }
#pragma unroll
      for (int ni = 0; ni < 4; ++ni) {
        const int row = wc * 64 + ni * 16 + fr;
        const int kb  = (kk * 64 + fk * 16) ^ ((row & 7) << 4);
        bfr[ni] = *(const short8*)((const char*)Bs + row * 128 + kb);
      }
#pragma unroll
      for (int mi = 0; mi < 4; ++mi)
#pragma unroll
        for (int ni = 0; ni < 4; ++ni)
          acc[mi][ni] = __builtin_amdgcn_mfma_f32_16x16x32_bf16(afr[mi], bfr[ni], acc[mi][ni], 0, 0, 0);
    }
  }

  // epilogue: C/D layout col = lane&15, row = (lane>>4)*4 + j
  const float* be = bias + (size_t)e * Nn;
#pragma unroll
  for (int ni = 0; ni < 4; ++ni) {
    const int col = n0 + wc * 64 + ni * 16 + fr;
    const float b = be[col];
#pragma unroll
    for (int mi = 0; mi < 4; ++mi) {
      const int rbase = m0 + wr * 64 + mi * 16 + fk * 4;
#pragma unroll
      for (int j = 0; j < 4; ++j) {
        float v = acc[mi][ni][j] + b;
        if (GELU_OUT) {
          v = 0.5f * v * (1.0f + erff(v * 0.70710678118654752f));
          ((__hip_bfloat16*)Cout)[(size_t)e * M * Nn + (size_t)(rbase + j) * Nn + col] =
              __float2bfloat16(v);
        } else {
          ((float*)Cout)[(size_t)e * M * Nn + (size_t)(rbase + j) * Nn + col] = v;
        }
      }
    }
  }
}

// ---------------------------------------------------------------------------
// K7: combine — out[n] = w0*exp_out[e0][s0] + w1*exp_out[e1][s1]
// ---------------------------------------------------------------------------
__global__ __launch_bounds__(256)
void combine_kernel(const float* __restrict__ eout, const int* __restrict__ eidx,
                    const float* __restrict__ pval, const int* __restrict__ slot,
                    float* __restrict__ out)
{
  const int wv = threadIdx.x >> 6, lane = threadIdx.x & 63;
  const int n = blockIdx.x * 4 + wv;
  const int e0 = eidx[n], e1 = eidx[N_TOK + n];
  int s0 = slot[n], s1 = slot[N_TOK + n];
  const float w0 = (s0 >= 0) ? pval[n] : 0.f;
  const float w1 = (s1 >= 0) ? pval[N_TOK + n] : 0.f;
  s0 = (s0 >= 0) ? s0 : 0;
  s1 = (s1 >= 0) ? s1 : 0;
  const float4* r0 = (const float4*)(eout + ((size_t)e0 * CAPC + s0) * CDIM);
  const float4* r1 = (const float4*)(eout + ((size_t)e1 * CAPC + s1) * CDIM);
  float4* o = (float4*)(out + (size_t)n * CDIM);
#pragma unroll
  for (int i = 0; i < 3; ++i) {
    const float4 a = r0[i * 64 + lane];
    const float4 b = r1[i * 64 + lane];
    float4 c;
    c.x = w0 * a.x + w1 * b.x;
    c.y = w0 * a.y + w1 * b.y;
    c.z = w0 * a.z + w1 * b.z;
    c.w = w0 * a.w + w1 * b.w;
    o[i * 64 + lane] = c;
  }
}

// ---------------------------------------------------------------------------
extern "C" void kernel_launch(void* const* d_in, const int* in_sizes, int n_in,
                              void* d_out, int out_size, void* d_ws, size_t ws_size,
                              hipStream_t stream)
{
  const float* x   = (const float*)d_in[0];
  const float* wg  = (const float*)d_in[1];
  const float* cfc = (const float*)d_in[2];
  const float* fcb = (const float*)d_in[3];
  const float* cpr = (const float*)d_in[4];
  const float* prb = (const float*)d_in[5];
  float* out = (float*)d_out;

  char* ws = (char*)d_ws;
  size_t off = 0;
  auto take = [&](size_t bytes) -> void* {
    void* p = ws + off;
    off += (bytes + 255) & ~(size_t)255;
    return p;
  };
  __hip_bfloat16* wfcT = (__hip_bfloat16*)take((size_t)E_EXP * HDIM * CDIM * 2); // [E][3072][768]
  __hip_bfloat16* wprT = (__hip_bfloat16*)take((size_t)E_EXP * CDIM * HDIM * 2); // [E][768][3072]
  __hip_bfloat16* xin  = (__hip_bfloat16*)take((size_t)E_EXP * CAPC * CDIM * 2); // [E][CAP][768]
  __hip_bfloat16* hbuf = (__hip_bfloat16*)take((size_t)E_EXP * CAPC * HDIM * 2); // [E][CAP][3072]
  float*          eout = (float*)take((size_t)E_EXP * CAPC * CDIM * 4);          // [E][CAP][768]
  int*   eidx = (int*)take((size_t)2 * N_TOK * 4);
  float* pv   = (float*)take((size_t)2 * N_TOK * 4);
  int*   slot = (int*)take((size_t)2 * N_TOK * 4);
  int*   stok = (int*)take((size_t)E_EXP * CAPC * 4);

  // weight transpose+convert: c_fc [8][768][3072] -> wfcT [8][3072][768]
  transpose_convert<<<dim3(HDIM / 32, CDIM / 32, E_EXP), 256, 0, stream>>>(cfc, wfcT, CDIM, HDIM);
  // c_proj [8][3072][768] -> wprT [8][768][3072]
  transpose_convert<<<dim3(CDIM / 32, HDIM / 32, E_EXP), 256, 0, stream>>>(cpr, wprT, HDIM, CDIM);

  router_kernel<<<N_TOK / 4, 256, 0, stream>>>(x, wg, eidx, pv);
  init_slots<<<(E_EXP * CAPC) / 256, 256, 0, stream>>>(stok);
  scan_kernel<<<1, 256, 0, stream>>>(eidx, slot, stok);
  dispatch_kernel<<<(E_EXP * CAPC) / 4, 256, 0, stream>>>(x, stok, xin);

  // GEMM1 + bias + exact GELU -> h (bf16)
  gemm_kernel<1><<<dim3(HDIM / 128, (E_EXP * CAPC) / (128 * E_EXP), E_EXP), 256, 0, stream>>>(
      xin, wfcT, fcb, hbuf, CAPC, HDIM, CDIM);
  // GEMM2 + bias -> exp_out (f32)
  gemm_kernel<0><<<dim3(CDIM / 128, CAPC / 128, E_EXP), 256, 0, stream>>>(
      hbuf, wprT, prb, eout, CAPC, CDIM, HDIM);

  combine_kernel<<<N_TOK / 4, 256, 0, stream>>>(eout, eidx, pv, slot, out);
}

// Round 2
// 311.799 us; speedup vs baseline: 1.0471x; 1.0471x over previous
//
#include <hip/hip_runtime.h>
#include <hip/hip_bf16.h>
#include <math.h>

// Problem constants (B=4, T=1024, C=768, E=8, K=2)
#define N_TOK 4096
#define CDIM  768
#define E_EXP 8
#define CAPC  2048
#define HDIM  3072   // 4*C

typedef __attribute__((ext_vector_type(8))) short short8;
typedef __attribute__((ext_vector_type(4))) float floatx4;

#define VMCNT(n) asm volatile("s_waitcnt vmcnt(" #n ")" ::: "memory")

static __device__ __forceinline__ unsigned short f2bf(float f) {
  __hip_bfloat16 h = __float2bfloat16(f);
  return __builtin_bit_cast(unsigned short, h);
}

// ---------------------------------------------------------------------------
// K1: transpose + f32->bf16 convert.  in: [E][R][Cc] f32 -> out: [E][Cc][R] bf16
// ---------------------------------------------------------------------------
__global__ __launch_bounds__(256)
void transpose_convert(const float* __restrict__ in, __hip_bfloat16* __restrict__ out,
                       int R, int Cc)
{
  __shared__ float tile[32][33];
  const int e  = blockIdx.z;
  const int c0 = blockIdx.x * 32;
  const int r0 = blockIdx.y * 32;
  const float* ie = in + (size_t)e * R * Cc;
  __hip_bfloat16* oe = out + (size_t)e * Cc * R;
  const int t = threadIdx.x;
  {
    const int r = t >> 3, c = (t & 7) * 4;
    const float4 v = *(const float4*)(ie + (size_t)(r0 + r) * Cc + c0 + c);
    tile[r][c + 0] = v.x; tile[r][c + 1] = v.y; tile[r][c + 2] = v.z; tile[r][c + 3] = v.w;
  }
  __syncthreads();
  {
    const int cc = t >> 3, rr = (t & 7) * 4;
    ushort4 o;
    o.x = f2bf(tile[rr + 0][cc]);
    o.y = f2bf(tile[rr + 1][cc]);
    o.z = f2bf(tile[rr + 2][cc]);
    o.w = f2bf(tile[rr + 3][cc]);
    *(ushort4*)((unsigned short*)oe + (size_t)(c0 + cc) * R + r0 + rr) = o;
  }
}

// ---------------------------------------------------------------------------
// K2: router — logits = x @ w_g^T, top-2 + softmax over the two kept logits.
// ---------------------------------------------------------------------------
__global__ __launch_bounds__(256)
void router_kernel(const float* __restrict__ x, const float* __restrict__ wg,
                   int* __restrict__ eidx, float* __restrict__ pval)
{
  const int wv = threadIdx.x >> 6, lane = threadIdx.x & 63;
  const int n = blockIdx.x * 4 + wv;
  const float* xr = x + (size_t)n * CDIM;
  float acc[E_EXP] = {0.f, 0.f, 0.f, 0.f, 0.f, 0.f, 0.f, 0.f};
#pragma unroll
  for (int i = 0; i < CDIM / 64; ++i) {
    const float xv = xr[i * 64 + lane];
#pragma unroll
    for (int e = 0; e < E_EXP; ++e)
      acc[e] = fmaf(xv, wg[e * CDIM + i * 64 + lane], acc[e]);
  }
#pragma unroll
  for (int e = 0; e < E_EXP; ++e) {
#pragma unroll
    for (int off = 32; off > 0; off >>= 1)
      acc[e] += __shfl_xor(acc[e], off);
  }
  if (lane == 0) {
    int e0 = 0; float v0 = acc[0];
#pragma unroll
    for (int e = 1; e < E_EXP; ++e) if (acc[e] > v0) { v0 = acc[e]; e0 = e; }
    int e1 = -1; float v1 = -3.4e38f;
#pragma unroll
    for (int e = 0; e < E_EXP; ++e) if (e != e0 && acc[e] > v1) { v1 = acc[e]; e1 = e; }
    const float ex = __expf(v1 - v0);
    const float inv = 1.f / (1.f + ex);
    eidx[n] = e0; eidx[N_TOK + n] = e1;
    pval[n] = inv; pval[N_TOK + n] = ex * inv;
  }
}

// ---------------------------------------------------------------------------
// K3: init slot_token to -1
// ---------------------------------------------------------------------------
__global__ void init_slots(int* __restrict__ p)
{
  p[blockIdx.x * 256 + threadIdx.x] = -1;
}

// ---------------------------------------------------------------------------
// K4: capacity scan (k-major reference order), single block Hillis-Steele.
// ---------------------------------------------------------------------------
__global__ __launch_bounds__(256)
void scan_kernel(const int* __restrict__ eidx, int* __restrict__ slot,
                 int* __restrict__ slot_token)
{
  const int t = threadIdx.x;
  const int base = t * 32;
  int e_local[32];
  int cnt[E_EXP] = {0, 0, 0, 0, 0, 0, 0, 0};
#pragma unroll
  for (int i = 0; i < 32; ++i) {
    const int e = eidx[base + i];
    e_local[i] = e;
    cnt[e]++;
  }
  __shared__ int hist[256][E_EXP];
#pragma unroll
  for (int e = 0; e < E_EXP; ++e) hist[t][e] = cnt[e];
  __syncthreads();
  for (int off = 1; off < 256; off <<= 1) {
    int v[E_EXP] = {0, 0, 0, 0, 0, 0, 0, 0};
    if (t >= off) {
#pragma unroll
      for (int e = 0; e < E_EXP; ++e) v[e] = hist[t - off][e];
    }
    __syncthreads();
    if (t >= off) {
#pragma unroll
      for (int e = 0; e < E_EXP; ++e) hist[t][e] += v[e];
    }
    __syncthreads();
  }
  int run[E_EXP];
#pragma unroll
  for (int e = 0; e < E_EXP; ++e) run[e] = hist[t][e] - cnt[e];
#pragma unroll
  for (int i = 0; i < 32; ++i) {
    const int a = base + i;
    const int e = e_local[i];
    const int r = run[e]++;
    const int s = (r < CAPC) ? r : -1;
    slot[a] = s;
    if (s >= 0) slot_token[e * CAPC + s] = (a < N_TOK) ? a : (a - N_TOK);
  }
}

// ---------------------------------------------------------------------------
// K5: dispatch — exp_in row = bf16(x[token]) or zeros.  One wave/slot.
// ---------------------------------------------------------------------------
__global__ __launch_bounds__(256)
void dispatch_kernel(const float* __restrict__ x, const int* __restrict__ slot_token,
                     __hip_bfloat16* __restrict__ xin)
{
  const int wv = threadIdx.x >> 6, lane = threadIdx.x & 63;
  const int s = blockIdx.x * 4 + wv;
  const int n = slot_token[s];
  unsigned short* orow = (unsigned short*)xin + (size_t)s * CDIM;
  if (n >= 0) {
    const float4* xr = (const float4*)(x + (size_t)n * CDIM);
#pragma unroll
    for (int i = 0; i < 3; ++i) {
      const float4 v = xr[i * 64 + lane];
      ushort4 o;
      o.x = f2bf(v.x); o.y = f2bf(v.y); o.z = f2bf(v.z); o.w = f2bf(v.w);
      *(ushort4*)(orow + (size_t)(i * 64 + lane) * 4) = o;
    }
  } else {
    const ushort4 z = {0, 0, 0, 0};
#pragma unroll
    for (int i = 0; i < 3; ++i)
      *(ushort4*)(orow + (size_t)(i * 64 + lane) * 4) = z;
  }
}

// ---------------------------------------------------------------------------
// K6: 256x256-tile deep-pipelined batched GEMM, BK=64, 8 waves (2Mx4N),
// 4 phases per K-tile (64x32 quadrant each), counted vmcnt, dbuf 128KiB LDS.
//
// LDS map (per buffer b = kt&1, 64 KiB):
//   A-half h (h = quadrant qm): local row li in [0,128): global m-row
//       gr = (li>>6)*128 + h*64 + (li&63); 128B rows, XOR swz (li&7)<<4.
//   B-half g (g = quadrant qn): local col lj: gc = (lj>>5)*64 + g*32 + (lj&31).
// Staging schedule (group kt = consume K-tile kt):
//   q0: stage A1(kt+1)   q1: B1(kt+1)   q2: A0(kt+2)   q3: B0(kt+2)
// vmcnt ledger: prologue {A0(0),B0(0),A1(0),B1(0),A0(1),B0(1)} then vmcnt(8);
//   steady vmcnt(6)@q0 (completes A1/B1(kt)), vmcnt(8)@q3 (A0/B0(kt+1));
//   tail groups (ntk-2, ntk-1) use (6,4) and (0,0).
// ---------------------------------------------------------------------------
__device__ __forceinline__ void stage_half(const __hip_bfloat16* Ae, const __hip_bfloat16* Be,
                                           char* lds, int K, int kt, int half,
                                           int wv, int lane)
{
  const int isB = half >> 1, hg = half & 1;
  const char* src = (const char*)(isB ? Be : Ae);
  char* ldst = lds + (kt & 1) * 65536 + isB * 32768 + hg * 16384;
#pragma unroll
  for (int j = 0; j < 2; ++j) {
    const int li = j * 64 + wv * 8 + (lane >> 3);
    const int gr = isB ? (((li >> 5) << 6) + hg * 32 + (li & 31))
                       : (((li >> 6) << 7) + hg * 64 + (li & 63));
    const int kb = ((lane & 7) * 16) ^ ((li & 7) << 4);  // pre-swizzled source
    const char* g = src + ((size_t)gr * K + (size_t)kt * 64) * 2 + kb;
    char* lp = ldst + j * 8192 + wv * 1024;  // + lane*16 implicit (HW scatter)
    __builtin_amdgcn_global_load_lds((const __attribute__((address_space(1))) unsigned int*)g,
                                     (__attribute__((address_space(3))) unsigned int*)lp, 16, 0, 0);
  }
}

template<int VM0, int VM3>
__device__ __forceinline__ void do_group(int kt, int ntk, char* lds,
                                         const __hip_bfloat16* Ae, const __hip_bfloat16* Be,
                                         int K, floatx4 (&acc)[8][4],
                                         int wm, int wn, int fr, int fk, int wv, int lane)
{
#pragma unroll
  for (int q = 0; q < 4; ++q) {
    const int qm = q >> 1, qn = q & 1;
    short8 afr[4][2], bfr[2][2];
    const char* Ab = lds + (kt & 1) * 65536 + qm * 16384;
    const char* Bb = lds + (kt & 1) * 65536 + 32768 + qn * 16384;
#pragma unroll
    for (int mi = 0; mi < 4; ++mi) {
      const int li = wm * 64 + mi * 16 + fr;
#pragma unroll
      for (int kk = 0; kk < 2; ++kk)
        afr[mi][kk] = *(const short8*)(Ab + li * 128 + ((kk * 64 + fk * 16) ^ ((li & 7) << 4)));
    }
#pragma unroll
    for (int ni = 0; ni < 2; ++ni) {
      const int lj = wn * 32 + ni * 16 + fr;
#pragma unroll
      for (int kk = 0; kk < 2; ++kk)
        bfr[ni][kk] = *(const short8*)(Bb + lj * 128 + ((kk * 64 + fk * 16) ^ ((lj & 7) << 4)));
    }
    if (q == 0 && kt + 1 < ntk) stage_half(Ae, Be, lds, K, kt + 1, 1, wv, lane);
    if (q == 1 && kt + 1 < ntk) stage_half(Ae, Be, lds, K, kt + 1, 3, wv, lane);
    if (q == 2 && kt + 2 < ntk) stage_half(Ae, Be, lds, K, kt + 2, 0, wv, lane);
    if (q == 3 && kt + 2 < ntk) stage_half(Ae, Be, lds, K, kt + 2, 2, wv, lane);
    if (q == 0) { if constexpr (VM0 == 6) VMCNT(6); else VMCNT(0); }
    if (q == 3) {
      if constexpr (VM3 == 8) VMCNT(8);
      else if constexpr (VM3 == 4) VMCNT(4);
      else VMCNT(0);
    }
    __builtin_amdgcn_s_barrier();
    asm volatile("s_waitcnt lgkmcnt(0)" ::: "memory");
    __builtin_amdgcn_sched_barrier(0);
    __builtin_amdgcn_s_setprio(1);
#pragma unroll
    for (int kk = 0; kk < 2; ++kk)
#pragma unroll
      for (int mi = 0; mi < 4; ++mi)
#pragma unroll
        for (int ni = 0; ni < 2; ++ni)
          acc[qm * 4 + mi][qn * 2 + ni] = __builtin_amdgcn_mfma_f32_16x16x32_bf16(
              afr[mi][kk], bfr[ni][kk], acc[qm * 4 + mi][qn * 2 + ni], 0, 0, 0);
    __builtin_amdgcn_s_setprio(0);
    __builtin_amdgcn_sched_barrier(0);
    __builtin_amdgcn_s_barrier();
    asm volatile("" ::: "memory");
  }
}

template<int GELU_OUT>
__global__ __launch_bounds__(512, 2)
void gemm8p(const __hip_bfloat16* __restrict__ A, const __hip_bfloat16* __restrict__ Bt,
            const float* __restrict__ bias, void* __restrict__ Cout,
            int M, int Nn, int K, int nbx, int nby)
{
  extern __shared__ __align__(16) char lds[];
  const int nwg = gridDim.x;
  int wg = blockIdx.x;
  wg = (wg & 7) * (nwg >> 3) + (wg >> 3);       // bijective XCD chunking (nwg%8==0)
  const int e = wg / (nbx * nby);
  const int rem = wg % (nbx * nby);
  const int by = rem / nbx, bx = rem % nbx;
  const int t = threadIdx.x, wv = t >> 6, lane = t & 63;
  const int wm = wv >> 2, wn = wv & 3;
  const int fr = lane & 15, fk = lane >> 4;
  const int ntk = K >> 6;

  const __hip_bfloat16* Ae = A + (size_t)e * M * K + (size_t)by * 256 * K;
  const __hip_bfloat16* Be = Bt + (size_t)e * Nn * K + (size_t)bx * 256 * K;

  floatx4 acc[8][4] = {};

  // prologue: FIFO {A0(0),B0(0),A1(0),B1(0),A0(1),B0(1)}
  stage_half(Ae, Be, lds, K, 0, 0, wv, lane);
  stage_half(Ae, Be, lds, K, 0, 2, wv, lane);
  stage_half(Ae, Be, lds, K, 0, 1, wv, lane);
  stage_half(Ae, Be, lds, K, 0, 3, wv, lane);
  stage_half(Ae, Be, lds, K, 1, 0, wv, lane);
  stage_half(Ae, Be, lds, K, 1, 2, wv, lane);
  VMCNT(8);
  __builtin_amdgcn_s_barrier();
  asm volatile("" ::: "memory");

  for (int kt = 0; kt < ntk - 2; ++kt)
    do_group<6, 8>(kt, ntk, lds, Ae, Be, K, acc, wm, wn, fr, fk, wv, lane);
  do_group<6, 4>(ntk - 2, ntk, lds, Ae, Be, K, acc, wm, wn, fr, fk, wv, lane);
  do_group<0, 0>(ntk - 1, ntk, lds, Ae, Be, K, acc, wm, wn, fr, fk, wv, lane);

  // epilogue: C/D layout col = lane&15, row = (lane>>4)*4 + j
  const float* be = bias + (size_t)e * Nn;
  const size_t cbase = (size_t)e * M * Nn;
  const int m0 = by * 256, n0 = bx * 256;
#pragma unroll
  for (int ni = 0; ni < 4; ++ni) {
    const int col = n0 + wn * 64 + ni * 16 + fr;
    const float b = be[col];
#pragma unroll
    for (int mi = 0; mi < 8; ++mi) {
      const int rbase = m0 + wm * 128 + mi * 16 + fk * 4;
#pragma unroll
      for (int j = 0; j < 4; ++j) {
        float v = acc[mi][ni][j] + b;
        if (GELU_OUT) {
          v = 0.5f * v * (1.0f + erff(v * 0.70710678118654752f));
          ((__hip_bfloat16*)Cout)[cbase + (size_t)(rbase + j) * Nn + col] = __float2bfloat16(v);
        } else {
          ((float*)Cout)[cbase + (size_t)(rbase + j) * Nn + col] = v;
        }
      }
    }
  }
}

// ---------------------------------------------------------------------------
// K7: combine — out[n] = w0*exp_out[e0][s0] + w1*exp_out[e1][s1]
// ---------------------------------------------------------------------------
__global__ __launch_bounds__(256)
void combine_kernel(const float* __restrict__ eout, const int* __restrict__ eidx,
                    const float* __restrict__ pval, const int* __restrict__ slot,
                    float* __restrict__ out)
{
  const int wv = threadIdx.x >> 6, lane = threadIdx.x & 63;
  const int n = blockIdx.x * 4 + wv;
  const int e0 = eidx[n], e1 = eidx[N_TOK + n];
  int s0 = slot[n], s1 = slot[N_TOK + n];
  const float w0 = (s0 >= 0) ? pval[n] : 0.f;
  const float w1 = (s1 >= 0) ? pval[N_TOK + n] : 0.f;
  s0 = (s0 >= 0) ? s0 : 0;
  s1 = (s1 >= 0) ? s1 : 0;
  const float4* r0 = (const float4*)(eout + ((size_t)e0 * CAPC + s0) * CDIM);
  const float4* r1 = (const float4*)(eout + ((size_t)e1 * CAPC + s1) * CDIM);
  float4* o = (float4*)(out + (size_t)n * CDIM);
#pragma unroll
  for (int i = 0; i < 3; ++i) {
    const float4 a = r0[i * 64 + lane];
    const float4 b = r1[i * 64 + lane];
    float4 c;
    c.x = w0 * a.x + w1 * b.x;
    c.y = w0 * a.y + w1 * b.y;
    c.z = w0 * a.z + w1 * b.z;
    c.w = w0 * a.w + w1 * b.w;
    o[i * 64 + lane] = c;
  }
}

// ---------------------------------------------------------------------------
extern "C" void kernel_launch(void* const* d_in, const int* in_sizes, int n_in,
                              void* d_out, int out_size, void* d_ws, size_t ws_size,
                              hipStream_t stream)
{
  const float* x   = (const float*)d_in[0];
  const float* wg  = (const float*)d_in[1];
  const float* cfc = (const float*)d_in[2];
  const float* fcb = (const float*)d_in[3];
  const float* cpr = (const float*)d_in[4];
  const float* prb = (const float*)d_in[5];
  float* out = (float*)d_out;

  char* ws = (char*)d_ws;
  size_t off = 0;
  auto take = [&](size_t bytes) -> void* {
    void* p = ws + off;
    off += (bytes + 255) & ~(size_t)255;
    return p;
  };
  __hip_bfloat16* wfcT = (__hip_bfloat16*)take((size_t)E_EXP * HDIM * CDIM * 2); // [E][3072][768]
  __hip_bfloat16* wprT = (__hip_bfloat16*)take((size_t)E_EXP * CDIM * HDIM * 2); // [E][768][3072]
  __hip_bfloat16* xin  = (__hip_bfloat16*)take((size_t)E_EXP * CAPC * CDIM * 2); // [E][CAP][768]
  __hip_bfloat16* hbuf = (__hip_bfloat16*)take((size_t)E_EXP * CAPC * HDIM * 2); // [E][CAP][3072]
  float*          eout = (float*)take((size_t)E_EXP * CAPC * CDIM * 4);          // [E][CAP][768]
  int*   eidx = (int*)take((size_t)2 * N_TOK * 4);
  float* pv   = (float*)take((size_t)2 * N_TOK * 4);
  int*   slot = (int*)take((size_t)2 * N_TOK * 4);
  int*   stok = (int*)take((size_t)E_EXP * CAPC * 4);

  hipFuncSetAttribute((const void*)gemm8p<1>, hipFuncAttributeMaxDynamicSharedMemorySize, 131072);
  hipFuncSetAttribute((const void*)gemm8p<0>, hipFuncAttributeMaxDynamicSharedMemorySize, 131072);

  // weight transpose+convert
  transpose_convert<<<dim3(HDIM / 32, CDIM / 32, E_EXP), 256, 0, stream>>>(cfc, wfcT, CDIM, HDIM);
  transpose_convert<<<dim3(CDIM / 32, HDIM / 32, E_EXP), 256, 0, stream>>>(cpr, wprT, HDIM, CDIM);

  router_kernel<<<N_TOK / 4, 256, 0, stream>>>(x, wg, eidx, pv);
  init_slots<<<(E_EXP * CAPC) / 256, 256, 0, stream>>>(stok);
  scan_kernel<<<1, 256, 0, stream>>>(eidx, slot, stok);
  dispatch_kernel<<<(E_EXP * CAPC) / 4, 256, 0, stream>>>(x, stok, xin);

  // GEMM1 + bias + exact GELU -> h (bf16): per-expert M=2048, N=3072, K=768
  gemm8p<1><<<768, 512, 131072, stream>>>(xin, wfcT, fcb, hbuf, CAPC, HDIM, CDIM, 12, 8);
  // GEMM2 + bias -> exp_out (f32): per-expert M=2048, N=768, K=3072
  gemm8p<0><<<192, 512, 131072, stream>>>(hbuf, wprT, prb, eout, CAPC, CDIM, HDIM, 3, 8);

  combine_kernel<<<N_TOK / 4, 256, 0, stream>>>(eout, eidx, pv, slot, out);
}

// Round 3
// 273.195 us; speedup vs baseline: 1.1951x; 1.1413x over previous
//
#include <hip/hip_runtime.h>
#include <hip/hip_bf16.h>
#include <math.h>

// Problem constants (B=4, T=1024, C=768, E=8, K=2)
#define N_TOK 4096
#define CDIM  768
#define E_EXP 8
#define CAPC  2048
#define HDIM  3072   // 4*C

typedef __attribute__((ext_vector_type(8))) short short8;
typedef __attribute__((ext_vector_type(4))) float floatx4;

#define VMCNT(n) asm volatile("s_waitcnt vmcnt(" #n ")" ::: "memory")

static __device__ __forceinline__ unsigned short f2bf(float f) {
  __hip_bfloat16 h = __float2bfloat16(f);
  return __builtin_bit_cast(unsigned short, h);
}

// ---------------------------------------------------------------------------
// K1: transpose + f32->bf16 convert.  in: [E][R][Cc] f32 -> out: [E][Cc][R] bf16
// ---------------------------------------------------------------------------
__global__ __launch_bounds__(256)
void transpose_convert(const float* __restrict__ in, __hip_bfloat16* __restrict__ out,
                       int R, int Cc)
{
  __shared__ float tile[32][33];
  const int e  = blockIdx.z;
  const int c0 = blockIdx.x * 32;
  const int r0 = blockIdx.y * 32;
  const float* ie = in + (size_t)e * R * Cc;
  __hip_bfloat16* oe = out + (size_t)e * Cc * R;
  const int t = threadIdx.x;
  {
    const int r = t >> 3, c = (t & 7) * 4;
    const float4 v = *(const float4*)(ie + (size_t)(r0 + r) * Cc + c0 + c);
    tile[r][c + 0] = v.x; tile[r][c + 1] = v.y; tile[r][c + 2] = v.z; tile[r][c + 3] = v.w;
  }
  __syncthreads();
  {
    const int cc = t >> 3, rr = (t & 7) * 4;
    ushort4 o;
    o.x = f2bf(tile[rr + 0][cc]);
    o.y = f2bf(tile[rr + 1][cc]);
    o.z = f2bf(tile[rr + 2][cc]);
    o.w = f2bf(tile[rr + 3][cc]);
    *(ushort4*)((unsigned short*)oe + (size_t)(c0 + cc) * R + r0 + rr) = o;
  }
}

// ---------------------------------------------------------------------------
// K2: router — logits = x @ w_g^T, top-2 + softmax over the two kept logits.
// ---------------------------------------------------------------------------
__global__ __launch_bounds__(256)
void router_kernel(const float* __restrict__ x, const float* __restrict__ wg,
                   int* __restrict__ eidx, float* __restrict__ pval)
{
  const int wv = threadIdx.x >> 6, lane = threadIdx.x & 63;
  const int n = blockIdx.x * 4 + wv;
  const float* xr = x + (size_t)n * CDIM;
  float acc[E_EXP] = {0.f, 0.f, 0.f, 0.f, 0.f, 0.f, 0.f, 0.f};
#pragma unroll
  for (int i = 0; i < CDIM / 64; ++i) {
    const float xv = xr[i * 64 + lane];
#pragma unroll
    for (int e = 0; e < E_EXP; ++e)
      acc[e] = fmaf(xv, wg[e * CDIM + i * 64 + lane], acc[e]);
  }
#pragma unroll
  for (int e = 0; e < E_EXP; ++e) {
#pragma unroll
    for (int off = 32; off > 0; off >>= 1)
      acc[e] += __shfl_xor(acc[e], off);
  }
  if (lane == 0) {
    int e0 = 0; float v0 = acc[0];
#pragma unroll
    for (int e = 1; e < E_EXP; ++e) if (acc[e] > v0) { v0 = acc[e]; e0 = e; }
    int e1 = -1; float v1 = -3.4e38f;
#pragma unroll
    for (int e = 0; e < E_EXP; ++e) if (e != e0 && acc[e] > v1) { v1 = acc[e]; e1 = e; }
    const float ex = __expf(v1 - v0);
    const float inv = 1.f / (1.f + ex);
    eidx[n] = e0; eidx[N_TOK + n] = e1;
    pval[n] = inv; pval[N_TOK + n] = ex * inv;
  }
}

// ---------------------------------------------------------------------------
// K3: init slot_token to -1
// ---------------------------------------------------------------------------
__global__ void init_slots(int* __restrict__ p)
{
  p[blockIdx.x * 256 + threadIdx.x] = -1;
}

// ---------------------------------------------------------------------------
// K4: capacity scan (k-major reference order), single block Hillis-Steele.
// ---------------------------------------------------------------------------
__global__ __launch_bounds__(256)
void scan_kernel(const int* __restrict__ eidx, int* __restrict__ slot,
                 int* __restrict__ slot_token)
{
  const int t = threadIdx.x;
  const int base = t * 32;
  int e_local[32];
  int cnt[E_EXP] = {0, 0, 0, 0, 0, 0, 0, 0};
#pragma unroll
  for (int i = 0; i < 32; ++i) {
    const int e = eidx[base + i];
    e_local[i] = e;
    cnt[e]++;
  }
  __shared__ int hist[256][E_EXP];
#pragma unroll
  for (int e = 0; e < E_EXP; ++e) hist[t][e] = cnt[e];
  __syncthreads();
  for (int off = 1; off < 256; off <<= 1) {
    int v[E_EXP] = {0, 0, 0, 0, 0, 0, 0, 0};
    if (t >= off) {
#pragma unroll
      for (int e = 0; e < E_EXP; ++e) v[e] = hist[t - off][e];
    }
    __syncthreads();
    if (t >= off) {
#pragma unroll
      for (int e = 0; e < E_EXP; ++e) hist[t][e] += v[e];
    }
    __syncthreads();
  }
  int run[E_EXP];
#pragma unroll
  for (int e = 0; e < E_EXP; ++e) run[e] = hist[t][e] - cnt[e];
#pragma unroll
  for (int i = 0; i < 32; ++i) {
    const int a = base + i;
    const int e = e_local[i];
    const int r = run[e]++;
    const int s = (r < CAPC) ? r : -1;
    slot[a] = s;
    if (s >= 0) slot_token[e * CAPC + s] = (a < N_TOK) ? a : (a - N_TOK);
  }
}

// ---------------------------------------------------------------------------
// K5: dispatch — exp_in row = bf16(x[token]) or zeros.  One wave/slot.
// ---------------------------------------------------------------------------
__global__ __launch_bounds__(256)
void dispatch_kernel(const float* __restrict__ x, const int* __restrict__ slot_token,
                     __hip_bfloat16* __restrict__ xin)
{
  const int wv = threadIdx.x >> 6, lane = threadIdx.x & 63;
  const int s = blockIdx.x * 4 + wv;
  const int n = slot_token[s];
  unsigned short* orow = (unsigned short*)xin + (size_t)s * CDIM;
  if (n >= 0) {
    const float4* xr = (const float4*)(x + (size_t)n * CDIM);
#pragma unroll
    for (int i = 0; i < 3; ++i) {
      const float4 v = xr[i * 64 + lane];
      ushort4 o;
      o.x = f2bf(v.x); o.y = f2bf(v.y); o.z = f2bf(v.z); o.w = f2bf(v.w);
      *(ushort4*)(orow + (size_t)(i * 64 + lane) * 4) = o;
    }
  } else {
    const ushort4 z = {0, 0, 0, 0};
#pragma unroll
    for (int i = 0; i < 3; ++i)
      *(ushort4*)(orow + (size_t)(i * 64 + lane) * 4) = z;
  }
}

// ---------------------------------------------------------------------------
// K6: 256x256-tile deep-pipelined batched GEMM, BK=64, 8 waves (2Mx4N),
// 4 phases per K-tile, counted vmcnt, dbuf 128KiB LDS.
// Register-reuse phase schedule (minimum 24 ds_read_b128 per K-tile per wave):
//   p0: read A0(8)+B0(4), stage A1(kt+1), MFMA A0xB0
//   p1: read B1(4)        stage B1(kt+1), MFMA A0xB1   (A0 reused from regs)
//   p2: read A1(8)        stage A0(kt+2), MFMA A1xB0   (B0 reused from regs)
//   p3: (no reads)        stage B0(kt+2), MFMA A1xB1   (A1,B1 reused)
// vmcnt ledger (instr counts; stage_half = 2 gload_lds):
//   prologue {A0(0),B0(0),A1(0),B1(0),A0(1),B0(1)} then vmcnt(8) -> A0/B0(0) done;
//   steady: vmcnt(6)@p0 -> A1/B1(kt) done (read p1/p2); vmcnt(8)@p3 -> A0/B0(kt+1);
//   tails <6,4> and <0,0>.
// ---------------------------------------------------------------------------
__device__ __forceinline__ void stage_half(const __hip_bfloat16* Ae, const __hip_bfloat16* Be,
                                           char* lds, int K, int kt, int half,
                                           int wv, int lane)
{
  const int isB = half >> 1, hg = half & 1;
  const char* src = (const char*)(isB ? Be : Ae);
  char* ldst = lds + (kt & 1) * 65536 + isB * 32768 + hg * 16384;
#pragma unroll
  for (int j = 0; j < 2; ++j) {
    const int li = j * 64 + wv * 8 + (lane >> 3);
    const int gr = isB ? (((li >> 5) << 6) + hg * 32 + (li & 31))
                       : (((li >> 6) << 7) + hg * 64 + (li & 63));
    const int kb = ((lane & 7) * 16) ^ ((li & 7) << 4);  // pre-swizzled source
    const char* g = src + ((size_t)gr * K + (size_t)kt * 64) * 2 + kb;
    char* lp = ldst + j * 8192 + wv * 1024;  // + lane*16 implicit (HW scatter)
    __builtin_amdgcn_global_load_lds((const __attribute__((address_space(1))) unsigned int*)g,
                                     (__attribute__((address_space(3))) unsigned int*)lp, 16, 0, 0);
  }
}

#define PHASE_SYNC_PRE()                                        \
  __builtin_amdgcn_s_barrier();                                 \
  asm volatile("s_waitcnt lgkmcnt(0)" ::: "memory");            \
  __builtin_amdgcn_sched_barrier(0);                            \
  __builtin_amdgcn_s_setprio(1)

#define PHASE_SYNC_POST()                                       \
  __builtin_amdgcn_s_setprio(0);                                \
  __builtin_amdgcn_sched_barrier(0);                            \
  __builtin_amdgcn_s_barrier()

template<int VM0, int VM3>
__device__ __forceinline__ void do_group(int kt, int ntk, char* lds,
                                         const __hip_bfloat16* Ae, const __hip_bfloat16* Be,
                                         int K, floatx4 (&acc)[8][4],
                                         int wm, int wn, int fr, int fk, int wv, int lane)
{
  const char* Ab = lds + (kt & 1) * 65536;
  const char* Bb = Ab + 32768;
  short8 a[4][2], b0[2][2], b1[2][2];

  // ---------------- phase 0: A0 x B0 ----------------
#pragma unroll
  for (int mi = 0; mi < 4; ++mi) {
    const int lr = wm * 64 + mi * 16 + fr;
#pragma unroll
    for (int kk = 0; kk < 2; ++kk)
      a[mi][kk] = *(const short8*)(Ab + lr * 128 + ((kk * 64 + fk * 16) ^ ((lr & 7) << 4)));
  }
#pragma unroll
  for (int ni = 0; ni < 2; ++ni) {
    const int lj = wn * 32 + ni * 16 + fr;
#pragma unroll
    for (int kk = 0; kk < 2; ++kk)
      b0[ni][kk] = *(const short8*)(Bb + lj * 128 + ((kk * 64 + fk * 16) ^ ((lj & 7) << 4)));
  }
  if (kt + 1 < ntk) stage_half(Ae, Be, lds, K, kt + 1, 1, wv, lane);
  if constexpr (VM0 == 6) VMCNT(6); else VMCNT(0);
  PHASE_SYNC_PRE();
#pragma unroll
  for (int kk = 0; kk < 2; ++kk)
#pragma unroll
    for (int mi = 0; mi < 4; ++mi)
#pragma unroll
      for (int ni = 0; ni < 2; ++ni)
        acc[mi][ni] = __builtin_amdgcn_mfma_f32_16x16x32_bf16(a[mi][kk], b0[ni][kk], acc[mi][ni], 0, 0, 0);
  PHASE_SYNC_POST();

  // ---------------- phase 1: A0 x B1 ----------------
#pragma unroll
  for (int ni = 0; ni < 2; ++ni) {
    const int lj = wn * 32 + ni * 16 + fr;
#pragma unroll
    for (int kk = 0; kk < 2; ++kk)
      b1[ni][kk] = *(const short8*)(Bb + 16384 + lj * 128 + ((kk * 64 + fk * 16) ^ ((lj & 7) << 4)));
  }
  if (kt + 1 < ntk) stage_half(Ae, Be, lds, K, kt + 1, 3, wv, lane);
  PHASE_SYNC_PRE();
#pragma unroll
  for (int kk = 0; kk < 2; ++kk)
#pragma unroll
    for (int mi = 0; mi < 4; ++mi)
#pragma unroll
      for (int ni = 0; ni < 2; ++ni)
        acc[mi][2 + ni] = __builtin_amdgcn_mfma_f32_16x16x32_bf16(a[mi][kk], b1[ni][kk], acc[mi][2 + ni], 0, 0, 0);
  PHASE_SYNC_POST();

  // ---------------- phase 2: A1 x B0 ----------------
#pragma unroll
  for (int mi = 0; mi < 4; ++mi) {
    const int lr = wm * 64 + mi * 16 + fr;
#pragma unroll
    for (int kk = 0; kk < 2; ++kk)
      a[mi][kk] = *(const short8*)(Ab + 16384 + lr * 128 + ((kk * 64 + fk * 16) ^ ((lr & 7) << 4)));
  }
  if (kt + 2 < ntk) stage_half(Ae, Be, lds, K, kt + 2, 0, wv, lane);
  PHASE_SYNC_PRE();
#pragma unroll
  for (int kk = 0; kk < 2; ++kk)
#pragma unroll
    for (int mi = 0; mi < 4; ++mi)
#pragma unroll
      for (int ni = 0; ni < 2; ++ni)
        acc[4 + mi][ni] = __builtin_amdgcn_mfma_f32_16x16x32_bf16(a[mi][kk], b0[ni][kk], acc[4 + mi][ni], 0, 0, 0);
  PHASE_SYNC_POST();

  // ---------------- phase 3: A1 x B1 ----------------
  if (kt + 2 < ntk) stage_half(Ae, Be, lds, K, kt + 2, 2, wv, lane);
  if constexpr (VM3 == 8) VMCNT(8);
  else if constexpr (VM3 == 4) VMCNT(4);
  else VMCNT(0);
  PHASE_SYNC_PRE();
#pragma unroll
  for (int kk = 0; kk < 2; ++kk)
#pragma unroll
    for (int mi = 0; mi < 4; ++mi)
#pragma unroll
      for (int ni = 0; ni < 2; ++ni)
        acc[4 + mi][2 + ni] = __builtin_amdgcn_mfma_f32_16x16x32_bf16(a[mi][kk], b1[ni][kk], acc[4 + mi][2 + ni], 0, 0, 0);
  PHASE_SYNC_POST();
  asm volatile("" ::: "memory");
}

template<int GELU_OUT>
__global__ __launch_bounds__(512, 2)
void gemm8p(const __hip_bfloat16* __restrict__ A, const __hip_bfloat16* __restrict__ Bt,
            const float* __restrict__ bias, void* __restrict__ Cout,
            int M, int Nn, int K, int nbx, int nby)
{
  extern __shared__ __align__(16) char lds[];
  const int nwg = gridDim.x;
  int wg = blockIdx.x;
  wg = (wg & 7) * (nwg >> 3) + (wg >> 3);       // bijective XCD chunking (nwg%8==0)
  const int e = wg / (nbx * nby);
  const int rem = wg % (nbx * nby);
  const int by = rem / nbx, bx = rem % nbx;
  const int t = threadIdx.x, wv = t >> 6, lane = t & 63;
  const int wm = wv >> 2, wn = wv & 3;
  const int fr = lane & 15, fk = lane >> 4;
  const int ntk = K >> 6;

  const __hip_bfloat16* Ae = A + (size_t)e * M * K + (size_t)by * 256 * K;
  const __hip_bfloat16* Be = Bt + (size_t)e * Nn * K + (size_t)bx * 256 * K;

  floatx4 acc[8][4] = {};

  // prologue: FIFO {A0(0),B0(0),A1(0),B1(0),A0(1),B0(1)}
  stage_half(Ae, Be, lds, K, 0, 0, wv, lane);
  stage_half(Ae, Be, lds, K, 0, 2, wv, lane);
  stage_half(Ae, Be, lds, K, 0, 1, wv, lane);
  stage_half(Ae, Be, lds, K, 0, 3, wv, lane);
  stage_half(Ae, Be, lds, K, 1, 0, wv, lane);
  stage_half(Ae, Be, lds, K, 1, 2, wv, lane);
  VMCNT(8);
  __builtin_amdgcn_s_barrier();
  asm volatile("" ::: "memory");

  for (int kt = 0; kt < ntk - 2; ++kt)
    do_group<6, 8>(kt, ntk, lds, Ae, Be, K, acc, wm, wn, fr, fk, wv, lane);
  do_group<6, 4>(ntk - 2, ntk, lds, Ae, Be, K, acc, wm, wn, fr, fk, wv, lane);
  do_group<0, 0>(ntk - 1, ntk, lds, Ae, Be, K, acc, wm, wn, fr, fk, wv, lane);

  // epilogue: C/D layout col = lane&15, row = (lane>>4)*4 + j
  const float* be = bias + (size_t)e * Nn;
  const size_t cbase = (size_t)e * M * Nn;
  const int m0 = by * 256, n0 = bx * 256;

  if (GELU_OUT) {
    // LDS-staged coalesced bf16 store (after final barrier, LDS is free;
    // each wave owns a private 2KB region -> no cross-wave sync needed).
    unsigned short* ep = (unsigned short*)(lds + wv * 2048);
    unsigned short* Cb = (unsigned short*)Cout + cbase;
    float bcol[4];
#pragma unroll
    for (int ni = 0; ni < 4; ++ni) bcol[ni] = be[n0 + wn * 64 + ni * 16 + fr];
#pragma unroll
    for (int mi = 0; mi < 8; ++mi) {
#pragma unroll
      for (int ni = 0; ni < 4; ++ni)
#pragma unroll
        for (int j = 0; j < 4; ++j) {
          float v = acc[mi][ni][j] + bcol[ni];
          v = 0.5f * v * (1.0f + erff(v * 0.70710678118654752f));
          const int row = fk * 4 + j;
          // XOR fk<<5: 4 fk-groups hit 4 disjoint 32B windows -> conflict-free
          *(unsigned short*)((char*)ep + row * 128 + ((ni * 32 + fr * 2) ^ (fk << 5))) = f2bf(v);
        }
      asm volatile("s_waitcnt lgkmcnt(0)" ::: "memory");
      __builtin_amdgcn_sched_barrier(0);
      const int r = lane & 15;
      const int grow = m0 + wm * 128 + mi * 16 + r;
#pragma unroll
      for (int it = 0; it < 2; ++it) {
        const int q = (lane >> 4) + it * 4;
        const short8 vv = *(const short8*)((char*)ep + r * 128 + ((q * 16) ^ ((r >> 2) << 5)));
        *(short8*)(Cb + (size_t)grow * Nn + n0 + wn * 64 + q * 8) = vv;
      }
      asm volatile("s_waitcnt lgkmcnt(0)" ::: "memory");
      __builtin_amdgcn_sched_barrier(0);
    }
  } else {
#pragma unroll
    for (int ni = 0; ni < 4; ++ni) {
      const int col = n0 + wn * 64 + ni * 16 + fr;
      const float b = be[col];
#pragma unroll
      for (int mi = 0; mi < 8; ++mi) {
        const int rbase = m0 + wm * 128 + mi * 16 + fk * 4;
#pragma unroll
        for (int j = 0; j < 4; ++j) {
          ((float*)Cout)[cbase + (size_t)(rbase + j) * Nn + col] = acc[mi][ni][j] + b;
        }
      }
    }
  }
}

// ---------------------------------------------------------------------------
// K7: combine — out[n] = w0*exp_out[e0][s0] + w1*exp_out[e1][s1]
// ---------------------------------------------------------------------------
__global__ __launch_bounds__(256)
void combine_kernel(const float* __restrict__ eout, const int* __restrict__ eidx,
                    const float* __restrict__ pval, const int* __restrict__ slot,
                    float* __restrict__ out)
{
  const int wv = threadIdx.x >> 6, lane = threadIdx.x & 63;
  const int n = blockIdx.x * 4 + wv;
  const int e0 = eidx[n], e1 = eidx[N_TOK + n];
  int s0 = slot[n], s1 = slot[N_TOK + n];
  const float w0 = (s0 >= 0) ? pval[n] : 0.f;
  const float w1 = (s1 >= 0) ? pval[N_TOK + n] : 0.f;
  s0 = (s0 >= 0) ? s0 : 0;
  s1 = (s1 >= 0) ? s1 : 0;
  const float4* r0 = (const float4*)(eout + ((size_t)e0 * CAPC + s0) * CDIM);
  const float4* r1 = (const float4*)(eout + ((size_t)e1 * CAPC + s1) * CDIM);
  float4* o = (float4*)(out + (size_t)n * CDIM);
#pragma unroll
  for (int i = 0; i < 3; ++i) {
    const float4 a = r0[i * 64 + lane];
    const float4 b = r1[i * 64 + lane];
    float4 c;
    c.x = w0 * a.x + w1 * b.x;
    c.y = w0 * a.y + w1 * b.y;
    c.z = w0 * a.z + w1 * b.z;
    c.w = w0 * a.w + w1 * b.w;
    o[i * 64 + lane] = c;
  }
}

// ---------------------------------------------------------------------------
extern "C" void kernel_launch(void* const* d_in, const int* in_sizes, int n_in,
                              void* d_out, int out_size, void* d_ws, size_t ws_size,
                              hipStream_t stream)
{
  const float* x   = (const float*)d_in[0];
  const float* wg  = (const float*)d_in[1];
  const float* cfc = (const float*)d_in[2];
  const float* fcb = (const float*)d_in[3];
  const float* cpr = (const float*)d_in[4];
  const float* prb = (const float*)d_in[5];
  float* out = (float*)d_out;

  char* ws = (char*)d_ws;
  size_t off = 0;
  auto take = [&](size_t bytes) -> void* {
    void* p = ws + off;
    off += (bytes + 255) & ~(size_t)255;
    return p;
  };
  __hip_bfloat16* wfcT = (__hip_bfloat16*)take((size_t)E_EXP * HDIM * CDIM * 2); // [E][3072][768]
  __hip_bfloat16* wprT = (__hip_bfloat16*)take((size_t)E_EXP * CDIM * HDIM * 2); // [E][768][3072]
  __hip_bfloat16* xin  = (__hip_bfloat16*)take((size_t)E_EXP * CAPC * CDIM * 2); // [E][CAP][768]
  __hip_bfloat16* hbuf = (__hip_bfloat16*)take((size_t)E_EXP * CAPC * HDIM * 2); // [E][CAP][3072]
  float*          eout = (float*)take((size_t)E_EXP * CAPC * CDIM * 4);          // [E][CAP][768]
  int*   eidx = (int*)take((size_t)2 * N_TOK * 4);
  float* pv   = (float*)take((size_t)2 * N_TOK * 4);
  int*   slot = (int*)take((size_t)2 * N_TOK * 4);
  int*   stok = (int*)take((size_t)E_EXP * CAPC * 4);

  hipFuncSetAttribute((const void*)gemm8p<1>, hipFuncAttributeMaxDynamicSharedMemorySize, 131072);
  hipFuncSetAttribute((const void*)gemm8p<0>, hipFuncAttributeMaxDynamicSharedMemorySize, 131072);

  // weight transpose+convert
  transpose_convert<<<dim3(HDIM / 32, CDIM / 32, E_EXP), 256, 0, stream>>>(cfc, wfcT, CDIM, HDIM);
  transpose_convert<<<dim3(CDIM / 32, HDIM / 32, E_EXP), 256, 0, stream>>>(cpr, wprT, HDIM, CDIM);

  router_kernel<<<N_TOK / 4, 256, 0, stream>>>(x, wg, eidx, pv);
  init_slots<<<(E_EXP * CAPC) / 256, 256, 0, stream>>>(stok);
  scan_kernel<<<1, 256, 0, stream>>>(eidx, slot, stok);
  dispatch_kernel<<<(E_EXP * CAPC) / 4, 256, 0, stream>>>(x, stok, xin);

  // GEMM1 + bias + exact GELU -> h (bf16): per-expert M=2048, N=3072, K=768
  gemm8p<1><<<768, 512, 131072, stream>>>(xin, wfcT, fcb, hbuf, CAPC, HDIM, CDIM, 12, 8);
  // GEMM2 + bias -> exp_out (f32): per-expert M=2048, N=768, K=3072
  gemm8p<0><<<192, 512, 131072, stream>>>(hbuf, wprT, prb, eout, CAPC, CDIM, HDIM, 3, 8);

  combine_kernel<<<N_TOK / 4, 256, 0, stream>>>(eout, eidx, pv, slot, out);
}

// Round 4
// 266.661 us; speedup vs baseline: 1.2243x; 1.0245x over previous
//
#include <hip/hip_runtime.h>
#include <hip/hip_bf16.h>
#include <math.h>

// Problem constants (B=4, T=1024, C=768, E=8, K=2)
#define N_TOK 4096
#define CDIM  768
#define E_EXP 8
#define CAPC  2048
#define HDIM  3072   // 4*C

typedef __attribute__((ext_vector_type(8))) short short8;
typedef __attribute__((ext_vector_type(4))) float floatx4;

#define VMCNT(n) asm volatile("s_waitcnt vmcnt(" #n ")" ::: "memory")
#define LGKM(n)  asm volatile("s_waitcnt lgkmcnt(" #n ")" ::: "memory")
#define SB0()    __builtin_amdgcn_sched_barrier(0)

static __device__ __forceinline__ unsigned short f2bf(float f) {
  __hip_bfloat16 h = __float2bfloat16(f);
  return __builtin_bit_cast(unsigned short, h);
}

// ---------------------------------------------------------------------------
// K1: transpose + f32->bf16 convert.  in: [E][R][Cc] f32 -> out: [E][Cc][R] bf16
// ---------------------------------------------------------------------------
__global__ __launch_bounds__(256)
void transpose_convert(const float* __restrict__ in, __hip_bfloat16* __restrict__ out,
                       int R, int Cc)
{
  __shared__ float tile[32][33];
  const int e  = blockIdx.z;
  const int c0 = blockIdx.x * 32;
  const int r0 = blockIdx.y * 32;
  const float* ie = in + (size_t)e * R * Cc;
  __hip_bfloat16* oe = out + (size_t)e * Cc * R;
  const int t = threadIdx.x;
  {
    const int r = t >> 3, c = (t & 7) * 4;
    const float4 v = *(const float4*)(ie + (size_t)(r0 + r) * Cc + c0 + c);
    tile[r][c + 0] = v.x; tile[r][c + 1] = v.y; tile[r][c + 2] = v.z; tile[r][c + 3] = v.w;
  }
  __syncthreads();
  {
    const int cc = t >> 3, rr = (t & 7) * 4;
    ushort4 o;
    o.x = f2bf(tile[rr + 0][cc]);
    o.y = f2bf(tile[rr + 1][cc]);
    o.z = f2bf(tile[rr + 2][cc]);
    o.w = f2bf(tile[rr + 3][cc]);
    *(ushort4*)((unsigned short*)oe + (size_t)(c0 + cc) * R + r0 + rr) = o;
  }
}

// ---------------------------------------------------------------------------
// K2: router — logits = x @ w_g^T, top-2 + softmax over the two kept logits.
// ---------------------------------------------------------------------------
__global__ __launch_bounds__(256)
void router_kernel(const float* __restrict__ x, const float* __restrict__ wg,
                   int* __restrict__ eidx, float* __restrict__ pval)
{
  const int wv = threadIdx.x >> 6, lane = threadIdx.x & 63;
  const int n = blockIdx.x * 4 + wv;
  const float* xr = x + (size_t)n * CDIM;
  float acc[E_EXP] = {0.f, 0.f, 0.f, 0.f, 0.f, 0.f, 0.f, 0.f};
#pragma unroll
  for (int i = 0; i < CDIM / 64; ++i) {
    const float xv = xr[i * 64 + lane];
#pragma unroll
    for (int e = 0; e < E_EXP; ++e)
      acc[e] = fmaf(xv, wg[e * CDIM + i * 64 + lane], acc[e]);
  }
#pragma unroll
  for (int e = 0; e < E_EXP; ++e) {
#pragma unroll
    for (int off = 32; off > 0; off >>= 1)
      acc[e] += __shfl_xor(acc[e], off);
  }
  if (lane == 0) {
    int e0 = 0; float v0 = acc[0];
#pragma unroll
    for (int e = 1; e < E_EXP; ++e) if (acc[e] > v0) { v0 = acc[e]; e0 = e; }
    int e1 = -1; float v1 = -3.4e38f;
#pragma unroll
    for (int e = 0; e < E_EXP; ++e) if (e != e0 && acc[e] > v1) { v1 = acc[e]; e1 = e; }
    const float ex = __expf(v1 - v0);
    const float inv = 1.f / (1.f + ex);
    eidx[n] = e0; eidx[N_TOK + n] = e1;
    pval[n] = inv; pval[N_TOK + n] = ex * inv;
  }
}

// ---------------------------------------------------------------------------
// K3: init slot_token to -1
// ---------------------------------------------------------------------------
__global__ void init_slots(int* __restrict__ p)
{
  p[blockIdx.x * 256 + threadIdx.x] = -1;
}

// ---------------------------------------------------------------------------
// K4: capacity scan (k-major reference order), single block Hillis-Steele.
// ---------------------------------------------------------------------------
__global__ __launch_bounds__(256)
void scan_kernel(const int* __restrict__ eidx, int* __restrict__ slot,
                 int* __restrict__ slot_token)
{
  const int t = threadIdx.x;
  const int base = t * 32;
  int e_local[32];
  int cnt[E_EXP] = {0, 0, 0, 0, 0, 0, 0, 0};
#pragma unroll
  for (int i = 0; i < 32; ++i) {
    const int e = eidx[base + i];
    e_local[i] = e;
    cnt[e]++;
  }
  __shared__ int hist[256][E_EXP];
#pragma unroll
  for (int e = 0; e < E_EXP; ++e) hist[t][e] = cnt[e];
  __syncthreads();
  for (int off = 1; off < 256; off <<= 1) {
    int v[E_EXP] = {0, 0, 0, 0, 0, 0, 0, 0};
    if (t >= off) {
#pragma unroll
      for (int e = 0; e < E_EXP; ++e) v[e] = hist[t - off][e];
    }
    __syncthreads();
    if (t >= off) {
#pragma unroll
      for (int e = 0; e < E_EXP; ++e) hist[t][e] += v[e];
    }
    __syncthreads();
  }
  int run[E_EXP];
#pragma unroll
  for (int e = 0; e < E_EXP; ++e) run[e] = hist[t][e] - cnt[e];
#pragma unroll
  for (int i = 0; i < 32; ++i) {
    const int a = base + i;
    const int e = e_local[i];
    const int r = run[e]++;
    const int s = (r < CAPC) ? r : -1;
    slot[a] = s;
    if (s >= 0) slot_token[e * CAPC + s] = (a < N_TOK) ? a : (a - N_TOK);
  }
}

// ---------------------------------------------------------------------------
// K5: dispatch — exp_in row = bf16(x[token]) or zeros.  One wave/slot.
// ---------------------------------------------------------------------------
__global__ __launch_bounds__(256)
void dispatch_kernel(const float* __restrict__ x, const int* __restrict__ slot_token,
                     __hip_bfloat16* __restrict__ xin)
{
  const int wv = threadIdx.x >> 6, lane = threadIdx.x & 63;
  const int s = blockIdx.x * 4 + wv;
  const int n = slot_token[s];
  unsigned short* orow = (unsigned short*)xin + (size_t)s * CDIM;
  if (n >= 0) {
    const float4* xr = (const float4*)(x + (size_t)n * CDIM);
#pragma unroll
    for (int i = 0; i < 3; ++i) {
      const float4 v = xr[i * 64 + lane];
      ushort4 o;
      o.x = f2bf(v.x); o.y = f2bf(v.y); o.z = f2bf(v.z); o.w = f2bf(v.w);
      *(ushort4*)(orow + (size_t)(i * 64 + lane) * 4) = o;
    }
  } else {
    const ushort4 z = {0, 0, 0, 0};
#pragma unroll
    for (int i = 0; i < 3; ++i)
      *(ushort4*)(orow + (size_t)(i * 64 + lane) * 4) = z;
  }
}

// ---------------------------------------------------------------------------
// K6: 256x256-tile batched GEMM, BK=64, 8 waves (2Mx4N), dbuf 128KiB LDS.
// Overlapped schedule: burst ds_reads + counted lgkmcnt, 2 barriers/K-tile.
//
// Per K-tile kt (buffer cur = kt&1, LDS regions A0|A1|B0|B1 @ 0|16K|32K|48K):
//   vmcnt(VME); barrier            // buffer kt fully staged & visible
//   issue reads A0(8),B0(4) ; B1(4); stage A1B1(kt+1) -> other buf
//   lgkm(4)  -> MFMA p0 (A0xB0)
//   issue reads A1(8)
//   lgkm(8)  -> MFMA p1 (A0xB1)
//   lgkm(0)  -> MFMA p2 (A1xB0)
//   barrier                        // all waves done reading cur buffer
//   stage A0B0(kt+2) -> cur buf ;  MFMA p3 (A1xB1, regs only)
// vmcnt FIFO ledger (units of 4 gloads): prologue [A0B0(0),A1B1(0),A0B0(1)];
//   steady entry vmcnt(4) completes exactly buffer kt; last iter vmcnt(0).
// ---------------------------------------------------------------------------
__device__ __forceinline__ void stage_half(const __hip_bfloat16* Ae, const __hip_bfloat16* Be,
                                           char* lds, int K, int kt, int half,
                                           int wv, int lane)
{
  const int isB = half >> 1, hg = half & 1;
  const char* src = (const char*)(isB ? Be : Ae);
  char* ldst = lds + (kt & 1) * 65536 + isB * 32768 + hg * 16384;
#pragma unroll
  for (int j = 0; j < 2; ++j) {
    const int li = j * 64 + wv * 8 + (lane >> 3);
    const int gr = isB ? (((li >> 5) << 6) + hg * 32 + (li & 31))
                       : (((li >> 6) << 7) + hg * 64 + (li & 63));
    const int kb = ((lane & 7) * 16) ^ ((li & 7) << 4);  // pre-swizzled source
    const char* g = src + ((size_t)gr * K + (size_t)kt * 64) * 2 + kb;
    char* lp = ldst + j * 8192 + wv * 1024;  // + lane*16 implicit (HW scatter)
    __builtin_amdgcn_global_load_lds((const __attribute__((address_space(1))) unsigned int*)g,
                                     (__attribute__((address_space(3))) unsigned int*)lp, 16, 0, 0);
  }
}

template<int VME, bool S1, bool S2>
__device__ __forceinline__ void ktile(int kt, char* lds,
                                      const __hip_bfloat16* Ae, const __hip_bfloat16* Be,
                                      int K, floatx4 (&acc)[8][4],
                                      int wm, int wn, int fr, int fk, int wv, int lane)
{
  if constexpr (VME == 4) VMCNT(4); else VMCNT(0);
  __builtin_amdgcn_s_barrier();
  SB0();
  const char* buf = lds + ((kt & 1) ? 65536 : 0);
  short8 a[4][2], b0[2][2], b1[2][2], a1[4][2];

  // reads: A0 (8 x b128), B0 (4 x b128)
#pragma unroll
  for (int mi = 0; mi < 4; ++mi) {
    const int lr = wm * 64 + mi * 16 + fr;
#pragma unroll
    for (int kk = 0; kk < 2; ++kk)
      a[mi][kk] = *(const short8*)(buf + lr * 128 + ((kk * 64 + fk * 16) ^ ((lr & 7) << 4)));
  }
#pragma unroll
  for (int ni = 0; ni < 2; ++ni) {
    const int lj = wn * 32 + ni * 16 + fr;
#pragma unroll
    for (int kk = 0; kk < 2; ++kk)
      b0[ni][kk] = *(const short8*)(buf + 32768 + lj * 128 + ((kk * 64 + fk * 16) ^ ((lj & 7) << 4)));
  }
  SB0();
  // reads: B1 (4 x b128)
#pragma unroll
  for (int ni = 0; ni < 2; ++ni) {
    const int lj = wn * 32 + ni * 16 + fr;
#pragma unroll
    for (int kk = 0; kk < 2; ++kk)
      b1[ni][kk] = *(const short8*)(buf + 49152 + lj * 128 + ((kk * 64 + fk * 16) ^ ((lj & 7) << 4)));
  }
  if (S1) {
    stage_half(Ae, Be, lds, K, kt + 1, 1, wv, lane);  // A1(kt+1)
    stage_half(Ae, Be, lds, K, kt + 1, 3, wv, lane);  // B1(kt+1)
  }
  SB0();
  LGKM(4); SB0();                      // A0,B0 resident (B1 may be in flight)
  __builtin_amdgcn_s_setprio(1);
#pragma unroll
  for (int kk = 0; kk < 2; ++kk)
#pragma unroll
    for (int mi = 0; mi < 4; ++mi)
#pragma unroll
      for (int ni = 0; ni < 2; ++ni)
        acc[mi][ni] = __builtin_amdgcn_mfma_f32_16x16x32_bf16(a[mi][kk], b0[ni][kk], acc[mi][ni], 0, 0, 0);
  __builtin_amdgcn_s_setprio(0);
  SB0();
  // reads: A1 (8 x b128) — drain overlaps p1/p2 MFMA
#pragma unroll
  for (int mi = 0; mi < 4; ++mi) {
    const int lr = wm * 64 + mi * 16 + fr;
#pragma unroll
    for (int kk = 0; kk < 2; ++kk)
      a1[mi][kk] = *(const short8*)(buf + 16384 + lr * 128 + ((kk * 64 + fk * 16) ^ ((lr & 7) << 4)));
  }
  SB0();
  LGKM(8); SB0();                      // B1 resident (A1 may be in flight)
  __builtin_amdgcn_s_setprio(1);
#pragma unroll
  for (int kk = 0; kk < 2; ++kk)
#pragma unroll
    for (int mi = 0; mi < 4; ++mi)
#pragma unroll
      for (int ni = 0; ni < 2; ++ni)
        acc[mi][2 + ni] = __builtin_amdgcn_mfma_f32_16x16x32_bf16(a[mi][kk], b1[ni][kk], acc[mi][2 + ni], 0, 0, 0);
  __builtin_amdgcn_s_setprio(0);
  SB0();
  LGKM(0); SB0();                      // A1 resident; ALL reads of cur buffer done
  __builtin_amdgcn_s_setprio(1);
#pragma unroll
  for (int kk = 0; kk < 2; ++kk)
#pragma unroll
    for (int mi = 0; mi < 4; ++mi)
#pragma unroll
      for (int ni = 0; ni < 2; ++ni)
        acc[4 + mi][ni] = __builtin_amdgcn_mfma_f32_16x16x32_bf16(a1[mi][kk], b0[ni][kk], acc[4 + mi][ni], 0, 0, 0);
  __builtin_amdgcn_s_setprio(0);
  SB0();
  __builtin_amdgcn_s_barrier();        // mid barrier: safe to overwrite cur A0/B0
  if (S2) {
    stage_half(Ae, Be, lds, K, kt + 2, 0, wv, lane);  // A0(kt+2)
    stage_half(Ae, Be, lds, K, kt + 2, 2, wv, lane);  // B0(kt+2)
  }
  SB0();
  __builtin_amdgcn_s_setprio(1);
#pragma unroll
  for (int kk = 0; kk < 2; ++kk)
#pragma unroll
    for (int mi = 0; mi < 4; ++mi)
#pragma unroll
      for (int ni = 0; ni < 2; ++ni)
        acc[4 + mi][2 + ni] = __builtin_amdgcn_mfma_f32_16x16x32_bf16(a1[mi][kk], b1[ni][kk], acc[4 + mi][2 + ni], 0, 0, 0);
  __builtin_amdgcn_s_setprio(0);
  SB0();
}

template<int GELU_OUT>
__global__ __launch_bounds__(512, 2)
void gemm8p(const __hip_bfloat16* __restrict__ A, const __hip_bfloat16* __restrict__ Bt,
            const float* __restrict__ bias, void* __restrict__ Cout,
            int M, int Nn, int K, int nbx, int nby)
{
  extern __shared__ __align__(16) char lds[];
  const int nwg = gridDim.x;
  int wg = blockIdx.x;
  wg = (wg & 7) * (nwg >> 3) + (wg >> 3);       // bijective XCD chunking (nwg%8==0)
  const int e = wg / (nbx * nby);
  const int rem = wg % (nbx * nby);
  const int by = rem / nbx, bx = rem % nbx;
  const int t = threadIdx.x, wv = t >> 6, lane = t & 63;
  const int wm = wv >> 2, wn = wv & 3;
  const int fr = lane & 15, fk = lane >> 4;
  const int ntk = K >> 6;

  const __hip_bfloat16* Ae = A + (size_t)e * M * K + (size_t)by * 256 * K;
  const __hip_bfloat16* Be = Bt + (size_t)e * Nn * K + (size_t)bx * 256 * K;

  floatx4 acc[8][4] = {};

  // prologue FIFO: [A0B0(0), A1B1(0), A0B0(1)]
  stage_half(Ae, Be, lds, K, 0, 0, wv, lane);
  stage_half(Ae, Be, lds, K, 0, 2, wv, lane);
  stage_half(Ae, Be, lds, K, 0, 1, wv, lane);
  stage_half(Ae, Be, lds, K, 0, 3, wv, lane);
  stage_half(Ae, Be, lds, K, 1, 0, wv, lane);
  stage_half(Ae, Be, lds, K, 1, 2, wv, lane);
  SB0();

  for (int kt = 0; kt < ntk - 2; ++kt)
    ktile<4, true, true>(kt, lds, Ae, Be, K, acc, wm, wn, fr, fk, wv, lane);
  ktile<4, true, false>(ntk - 2, lds, Ae, Be, K, acc, wm, wn, fr, fk, wv, lane);
  ktile<0, false, false>(ntk - 1, lds, Ae, Be, K, acc, wm, wn, fr, fk, wv, lane);

  // epilogue: C/D layout col = lane&15, row = (lane>>4)*4 + j
  const float* be = bias + (size_t)e * Nn;
  const size_t cbase = (size_t)e * M * Nn;
  const int m0 = by * 256, n0 = bx * 256;

  if (GELU_OUT) {
    // LDS-staged coalesced bf16 store; final barrier of K-loop passed, LDS free;
    // each wave owns a private 2KB region.
    __builtin_amdgcn_s_barrier();
    unsigned short* ep = (unsigned short*)(lds + wv * 2048);
    unsigned short* Cb = (unsigned short*)Cout + cbase;
    float bcol[4];
#pragma unroll
    for (int ni = 0; ni < 4; ++ni) bcol[ni] = be[n0 + wn * 64 + ni * 16 + fr];
#pragma unroll
    for (int mi = 0; mi < 8; ++mi) {
#pragma unroll
      for (int ni = 0; ni < 4; ++ni)
#pragma unroll
        for (int j = 0; j < 4; ++j) {
          float v = acc[mi][ni][j] + bcol[ni];
          v = 0.5f * v * (1.0f + erff(v * 0.70710678118654752f));
          const int row = fk * 4 + j;
          *(unsigned short*)((char*)ep + row * 128 + ((ni * 32 + fr * 2) ^ (fk << 5))) = f2bf(v);
        }
      LGKM(0); SB0();
      const int r = lane & 15;
      const int grow = m0 + wm * 128 + mi * 16 + r;
#pragma unroll
      for (int it = 0; it < 2; ++it) {
        const int q = (lane >> 4) + it * 4;
        const short8 vv = *(const short8*)((char*)ep + r * 128 + ((q * 16) ^ ((r >> 2) << 5)));
        *(short8*)(Cb + (size_t)grow * Nn + n0 + wn * 64 + q * 8) = vv;
      }
      LGKM(0); SB0();
    }
  } else {
#pragma unroll
    for (int ni = 0; ni < 4; ++ni) {
      const int col = n0 + wn * 64 + ni * 16 + fr;
      const float b = be[col];
#pragma unroll
      for (int mi = 0; mi < 8; ++mi) {
        const int rbase = m0 + wm * 128 + mi * 16 + fk * 4;
#pragma unroll
        for (int j = 0; j < 4; ++j) {
          ((float*)Cout)[cbase + (size_t)(rbase + j) * Nn + col] = acc[mi][ni][j] + b;
        }
      }
    }
  }
}

// ---------------------------------------------------------------------------
// K7: combine — out[n] = w0*exp_out[e0][s0] + w1*exp_out[e1][s1]
// ---------------------------------------------------------------------------
__global__ __launch_bounds__(256)
void combine_kernel(const float* __restrict__ eout, const int* __restrict__ eidx,
                    const float* __restrict__ pval, const int* __restrict__ slot,
                    float* __restrict__ out)
{
  const int wv = threadIdx.x >> 6, lane = threadIdx.x & 63;
  const int n = blockIdx.x * 4 + wv;
  const int e0 = eidx[n], e1 = eidx[N_TOK + n];
  int s0 = slot[n], s1 = slot[N_TOK + n];
  const float w0 = (s0 >= 0) ? pval[n] : 0.f;
  const float w1 = (s1 >= 0) ? pval[N_TOK + n] : 0.f;
  s0 = (s0 >= 0) ? s0 : 0;
  s1 = (s1 >= 0) ? s1 : 0;
  const float4* r0 = (const float4*)(eout + ((size_t)e0 * CAPC + s0) * CDIM);
  const float4* r1 = (const float4*)(eout + ((size_t)e1 * CAPC + s1) * CDIM);
  float4* o = (float4*)(out + (size_t)n * CDIM);
#pragma unroll
  for (int i = 0; i < 3; ++i) {
    const float4 a = r0[i * 64 + lane];
    const float4 b = r1[i * 64 + lane];
    float4 c;
    c.x = w0 * a.x + w1 * b.x;
    c.y = w0 * a.y + w1 * b.y;
    c.z = w0 * a.z + w1 * b.z;
    c.w = w0 * a.w + w1 * b.w;
    o[i * 64 + lane] = c;
  }
}

// ---------------------------------------------------------------------------
extern "C" void kernel_launch(void* const* d_in, const int* in_sizes, int n_in,
                              void* d_out, int out_size, void* d_ws, size_t ws_size,
                              hipStream_t stream)
{
  const float* x   = (const float*)d_in[0];
  const float* wg  = (const float*)d_in[1];
  const float* cfc = (const float*)d_in[2];
  const float* fcb = (const float*)d_in[3];
  const float* cpr = (const float*)d_in[4];
  const float* prb = (const float*)d_in[5];
  float* out = (float*)d_out;

  char* ws = (char*)d_ws;
  size_t off = 0;
  auto take = [&](size_t bytes) -> void* {
    void* p = ws + off;
    off += (bytes + 255) & ~(size_t)255;
    return p;
  };
  __hip_bfloat16* wfcT = (__hip_bfloat16*)take((size_t)E_EXP * HDIM * CDIM * 2); // [E][3072][768]
  __hip_bfloat16* wprT = (__hip_bfloat16*)take((size_t)E_EXP * CDIM * HDIM * 2); // [E][768][3072]
  __hip_bfloat16* xin  = (__hip_bfloat16*)take((size_t)E_EXP * CAPC * CDIM * 2); // [E][CAP][768]
  __hip_bfloat16* hbuf = (__hip_bfloat16*)take((size_t)E_EXP * CAPC * HDIM * 2); // [E][CAP][3072]
  float*          eout = (float*)take((size_t)E_EXP * CAPC * CDIM * 4);          // [E][CAP][768]
  int*   eidx = (int*)take((size_t)2 * N_TOK * 4);
  float* pv   = (float*)take((size_t)2 * N_TOK * 4);
  int*   slot = (int*)take((size_t)2 * N_TOK * 4);
  int*   stok = (int*)take((size_t)E_EXP * CAPC * 4);

  hipFuncSetAttribute((const void*)gemm8p<1>, hipFuncAttributeMaxDynamicSharedMemorySize, 131072);
  hipFuncSetAttribute((const void*)gemm8p<0>, hipFuncAttributeMaxDynamicSharedMemorySize, 131072);

  // weight transpose+convert
  transpose_convert<<<dim3(HDIM / 32, CDIM / 32, E_EXP), 256, 0, stream>>>(cfc, wfcT, CDIM, HDIM);
  transpose_convert<<<dim3(CDIM / 32, HDIM / 32, E_EXP), 256, 0, stream>>>(cpr, wprT, HDIM, CDIM);

  router_kernel<<<N_TOK / 4, 256, 0, stream>>>(x, wg, eidx, pv);
  init_slots<<<(E_EXP * CAPC) / 256, 256, 0, stream>>>(stok);
  scan_kernel<<<1, 256, 0, stream>>>(eidx, slot, stok);
  dispatch_kernel<<<(E_EXP * CAPC) / 4, 256, 0, stream>>>(x, stok, xin);

  // GEMM1 + bias + exact GELU -> h (bf16): per-expert M=2048, N=3072, K=768
  gemm8p<1><<<768, 512, 131072, stream>>>(xin, wfcT, fcb, hbuf, CAPC, HDIM, CDIM, 12, 8);
  // GEMM2 + bias -> exp_out (f32): per-expert M=2048, N=768, K=3072
  gemm8p<0><<<192, 512, 131072, stream>>>(hbuf, wprT, prb, eout, CAPC, CDIM, HDIM, 3, 8);

  combine_kernel<<<N_TOK / 4, 256, 0, stream>>>(eout, eidx, pv, slot, out);
}